// Round 2
// baseline (431.088 us; speedup 1.0000x reference)
//
#include <hip/hip_runtime.h>

typedef unsigned short u16;
typedef __attribute__((ext_vector_type(8))) __bf16 bf16x8;
typedef __attribute__((ext_vector_type(4))) float f32x4;
typedef __attribute__((ext_vector_type(4))) u16 u16x4;

#define NB 4
#define NQ 2048
#define NKV 1024
#define NH 16
#define DH 64
#define DIN 1024   // INNER = h*d = query dim
#define DCTX 768
#define ATT_SCALE 0.125f
#define NEGBIG -1e30f

__device__ inline u16 f2bf(float f) {
  unsigned u = __builtin_bit_cast(unsigned, f);
  u += 0x7FFFu + ((u >> 16) & 1u);   // RNE (no NaN inputs here)
  return (u16)(u >> 16);
}

// ---------------- mask dtype detection + bias build ----------------
// mask is [4][1024] of {bool8 | int32 | float32} — harness dtype mapping for
// jnp.bool_ is ambiguous. Detect from first 1024 words (in-bounds for all):
//   all words in {0,1}            -> int32
//   all words in {0,0x3f800000}   -> float32
//   else                          -> bytes
__global__ __launch_bounds__(256) void build_bias(const void* __restrict__ mask,
                                                  float* __restrict__ biasg) {
  __shared__ int notInt, notFloat;
  if (threadIdx.x == 0) { notInt = 0; notFloat = 0; }
  __syncthreads();
  const unsigned* mw = (const unsigned*)mask;
  int bad_i = 0, bad_f = 0;
#pragma unroll
  for (int e = 0; e < 4; e++) {
    unsigned v = mw[threadIdx.x * 4 + e];
    if (v > 1u) bad_i = 1;
    if (v != 0u && v != 0x3f800000u) bad_f = 1;
  }
  if (bad_i) atomicOr(&notInt, 1);
  if (bad_f) atomicOr(&notFloat, 1);
  __syncthreads();
  const int isInt = !notInt, isFloat = !notFloat;
  for (int i = threadIdx.x; i < NB * NKV; i += 256) {
    bool on;
    if (isInt)        on = ((const int*)mask)[i] != 0;
    else if (isFloat) on = ((const float*)mask)[i] != 0.f;
    else              on = ((const unsigned char*)mask)[i] != 0;
    biasg[i] = on ? 0.f : NEGBIG;
  }
}

// ---------------- fp32 -> bf16 elementwise ----------------
__global__ __launch_bounds__(256) void cvt_bf16(const float* __restrict__ in,
                                                u16* __restrict__ out, int n) {
  int i = (blockIdx.x * 256 + threadIdx.x) * 4;
  if (i >= n) return;
  float4 v = *(const float4*)(in + i);
  u16x4 o = { f2bf(v.x), f2bf(v.y), f2bf(v.z), f2bf(v.w) };
  *(u16x4*)(out + i) = o;
}

// ---------------- W[K][N] fp32 -> Wt[N][K] bf16 ----------------
__global__ __launch_bounds__(256) void transpose_cvt(const float* __restrict__ W,
                                                     u16* __restrict__ Wt, int K, int N) {
  __shared__ float tile[32][33];
  int n0 = blockIdx.x * 32, k0 = blockIdx.y * 32;
  int tx = threadIdx.x & 31, ty = threadIdx.x >> 5;  // 32 x 8
#pragma unroll
  for (int i = 0; i < 32; i += 8)
    tile[ty + i][tx] = W[(size_t)(k0 + ty + i) * N + n0 + tx];
  __syncthreads();
#pragma unroll
  for (int i = 0; i < 32; i += 8)
    Wt[(size_t)(n0 + ty + i) * K + k0 + tx] = f2bf(tile[tx][ty + i]);
}

// ---------------- bf16 GEMM: C[M][N] = A[M][K] * Bt[N][K]^T ----------------
// m97 structure: 128x128 tile, BK=32, 4 waves (2x2), 4x4 16x16x32 MFMA per wave,
// global_load_lds width 16.
template<int STORE_BF16>
__global__ __launch_bounds__(256) void gemm_bt(const u16* __restrict__ A,
                                               const u16* __restrict__ Bt,
                                               void* __restrict__ Cout,
                                               const float* __restrict__ bias,
                                               int M, int N, int K) {
  __shared__ __align__(16) u16 As[128 * 32];
  __shared__ __align__(16) u16 Bs[128 * 32];
  const int t = threadIdx.x, w = t >> 6, l = t & 63, g = l >> 4, m16 = l & 15;
  const int brow = blockIdx.y * 128, bcol = blockIdx.x * 128;
  const int wr = w >> 1, wc = w & 1;
  const int r_a = t >> 2;        // 0..63 row within 64-row half
  const int kb  = (t & 3) * 8;   // element offset within BK=32
  f32x4 acc[4][4] = {};

  for (int k0 = 0; k0 < K; k0 += 32) {
#pragma unroll
    for (int i = 0; i < 2; i++) {
      const u16* ga = A + (size_t)(brow + i * 64 + r_a) * K + k0 + kb;
      __builtin_amdgcn_global_load_lds((const __attribute__((address_space(1))) void*)ga,
          (__attribute__((address_space(3))) void*)((char*)As + i * 4096 + w * 1024), 16, 0, 0);
      const u16* gb = Bt + (size_t)(bcol + i * 64 + r_a) * K + k0 + kb;
      __builtin_amdgcn_global_load_lds((const __attribute__((address_space(1))) void*)gb,
          (__attribute__((address_space(3))) void*)((char*)Bs + i * 4096 + w * 1024), 16, 0, 0);
    }
    __syncthreads();
    bf16x8 af[4], bfr[4];
#pragma unroll
    for (int m = 0; m < 4; m++)
      af[m] = *(const bf16x8*)(As + (wr * 64 + m * 16 + m16) * 32 + g * 8);
#pragma unroll
    for (int n = 0; n < 4; n++)
      bfr[n] = *(const bf16x8*)(Bs + (wc * 64 + n * 16 + m16) * 32 + g * 8);
#pragma unroll
    for (int m = 0; m < 4; m++)
#pragma unroll
      for (int n = 0; n < 4; n++)
        acc[m][n] = __builtin_amdgcn_mfma_f32_16x16x32_bf16(af[m], bfr[n], acc[m][n], 0, 0, 0);
    __syncthreads();
  }
#pragma unroll
  for (int m = 0; m < 4; m++) {
    int grow = brow + wr * 64 + m * 16 + g * 4;
#pragma unroll
    for (int n = 0; n < 4; n++) {
      int gcol = bcol + wc * 64 + n * 16 + m16;
#pragma unroll
      for (int r = 0; r < 4; r++) {
        size_t off = (size_t)(grow + r) * N + gcol;
        if (STORE_BF16) ((u16*)Cout)[off] = f2bf(acc[m][n][r]);
        else            ((float*)Cout)[off] = acc[m][n][r] + bias[gcol];
      }
    }
  }
}

// ---------------- flash attention ----------------
// grid (32 qtiles, 16 heads, 4 batch), 256 thr = 4 waves, QBLK=64 (16 rows/wave), KVBLK=32
__global__ __launch_bounds__(256) void attn(const u16* __restrict__ Q, const u16* __restrict__ Kb,
                                            const u16* __restrict__ Vb,
                                            const float* __restrict__ biasg,
                                            u16* __restrict__ O) {
  const int qt = blockIdx.x, h = blockIdx.y, b = blockIdx.z;
  const int t = threadIdx.x, w = t >> 6, l = t & 63, g = l >> 4, m16 = l & 15;

  __shared__ __align__(16) u16 Kl[32][80];      // KVBLK x d, padded to 160B rows
  __shared__ __align__(16) u16 Vt[64][40];      // d x KVBLK (transposed), 80B rows
  __shared__ __align__(16) u16 Pl[4][16][40];   // per-wave P tile, 80B rows
  __shared__ float biasl[NKV];

  for (int i = t; i < NKV; i += 256)
    biasl[i] = biasg[(size_t)b * NKV + i];

  const int qrow = qt * 64 + w * 16 + m16;
  const u16* qp = Q + (size_t)(b * NQ + qrow) * DIN + h * DH;
  bf16x8 qf0 = *(const bf16x8*)(qp + g * 8);
  bf16x8 qf1 = *(const bf16x8*)(qp + 32 + g * 8);

  f32x4 oacc[4] = {};
  float m_run[4], l_run[4];
#pragma unroll
  for (int r = 0; r < 4; r++) { m_run[r] = NEGBIG; l_run[r] = 0.f; }

  const int jr = t >> 3;         // 0..31 staging row
  const int ce = (t & 7) * 8;    // 0..56 d-offset
  __syncthreads();

  for (int j0 = 0; j0 < NKV; j0 += 32) {
    { // stage K row-major (padded) and V transposed
      const u16* gk = Kb + (size_t)(b * NKV + j0 + jr) * DIN + h * DH + ce;
      *(int4*)&Kl[jr][ce] = *(const int4*)gk;
      const u16* gv = Vb + (size_t)(b * NKV + j0 + jr) * DIN + h * DH + ce;
      int4 vv = *(const int4*)gv;
      const u16* vp = (const u16*)&vv;
#pragma unroll
      for (int e = 0; e < 8; e++) Vt[ce + e][jr] = vp[e];
    }
    __syncthreads();

    float p0[4], p1[4], tmax[4];
    {
      f32x4 s0 = {}, s1 = {};
      bf16x8 kf;
      kf = *(const bf16x8*)&Kl[m16][g * 8];
      s0 = __builtin_amdgcn_mfma_f32_16x16x32_bf16(qf0, kf, s0, 0, 0, 0);
      kf = *(const bf16x8*)&Kl[m16][32 + g * 8];
      s0 = __builtin_amdgcn_mfma_f32_16x16x32_bf16(qf1, kf, s0, 0, 0, 0);
      kf = *(const bf16x8*)&Kl[16 + m16][g * 8];
      s1 = __builtin_amdgcn_mfma_f32_16x16x32_bf16(qf0, kf, s1, 0, 0, 0);
      kf = *(const bf16x8*)&Kl[16 + m16][32 + g * 8];
      s1 = __builtin_amdgcn_mfma_f32_16x16x32_bf16(qf1, kf, s1, 0, 0, 0);
      float b0 = biasl[j0 + m16], b1 = biasl[j0 + 16 + m16];
#pragma unroll
      for (int r = 0; r < 4; r++) {
        p0[r] = s0[r] * ATT_SCALE + b0;
        p1[r] = s1[r] * ATT_SCALE + b1;
        tmax[r] = fmaxf(p0[r], p1[r]);
      }
    }
#pragma unroll
    for (int r = 0; r < 4; r++) {  // row-max across 16 lanes of the group
      float v = tmax[r];
      v = fmaxf(v, __shfl_xor(v, 1));
      v = fmaxf(v, __shfl_xor(v, 2));
      v = fmaxf(v, __shfl_xor(v, 4));
      v = fmaxf(v, __shfl_xor(v, 8));
      tmax[r] = v;
    }
    float scf[4], psum[4];
#pragma unroll
    for (int r = 0; r < 4; r++) {
      float mn = fmaxf(m_run[r], tmax[r]);
      scf[r] = __expf(m_run[r] - mn);
      m_run[r] = mn;
      p0[r] = __expf(p0[r] - mn);
      p1[r] = __expf(p1[r] - mn);
      psum[r] = p0[r] + p1[r];
    }
#pragma unroll
    for (int r = 0; r < 4; r++) {
      float v = psum[r];
      v += __shfl_xor(v, 1);
      v += __shfl_xor(v, 2);
      v += __shfl_xor(v, 4);
      v += __shfl_xor(v, 8);
      l_run[r] = l_run[r] * scf[r] + v;
    }
#pragma unroll
    for (int dt = 0; dt < 4; dt++)
#pragma unroll
      for (int r = 0; r < 4; r++) oacc[dt][r] *= scf[r];
    // P -> LDS (per-wave region), re-read as A-fragment
#pragma unroll
    for (int r = 0; r < 4; r++) {
      Pl[w][g * 4 + r][m16]      = f2bf(p0[r]);
      Pl[w][g * 4 + r][16 + m16] = f2bf(p1[r]);
    }
    bf16x8 pf = *(const bf16x8*)&Pl[w][m16][g * 8];
#pragma unroll
    for (int dt = 0; dt < 4; dt++) {
      bf16x8 vf = *(const bf16x8*)&Vt[dt * 16 + m16][g * 8];
      oacc[dt] = __builtin_amdgcn_mfma_f32_16x16x32_bf16(pf, vf, oacc[dt], 0, 0, 0);
    }
    __syncthreads();
  }

  float inv[4];
#pragma unroll
  for (int r = 0; r < 4; r++) inv[r] = 1.f / l_run[r];
  u16* op = O + (size_t)(b * NQ + qt * 64 + w * 16) * DIN + h * DH;
#pragma unroll
  for (int dt = 0; dt < 4; dt++)
#pragma unroll
    for (int r = 0; r < 4; r++)
      op[(size_t)(g * 4 + r) * DIN + dt * 16 + m16] = f2bf(oacc[dt][r] * inv[r]);
}

// ---------------- launcher ----------------
extern "C" void kernel_launch(void* const* d_in, const int* in_sizes, int n_in,
                              void* d_out, int out_size, void* d_ws, size_t ws_size,
                              hipStream_t stream) {
  const float* x   = (const float*)d_in[0];
  const float* ctx = (const float*)d_in[1];
  const void*  mask = (const void*)d_in[2];
  const float* Wq  = (const float*)d_in[3];
  const float* Wk  = (const float*)d_in[4];
  const float* Wv  = (const float*)d_in[5];
  const float* Wo  = (const float*)d_in[6];
  const float* bo  = (const float*)d_in[7];
  float* out = (float*)d_out;

  char* ws = (char*)d_ws;
  u16* xb  = (u16*)(ws);                 // [8192][1024] bf16 (reused as ab after Q GEMM)
  u16* cb  = (u16*)(ws + 16777216);      // [4096][768]
  u16* wqt = (u16*)(ws + 23068672);      // [1024][1024]
  u16* wkt = (u16*)(ws + 25165824);      // [1024][768]
  u16* wvt = (u16*)(ws + 26738688);      // [1024][768]
  u16* wot = (u16*)(ws + 28311552);      // [1024][1024]
  u16* qb  = (u16*)(ws + 30408704);      // [8192][1024]
  u16* kb  = (u16*)(ws + 47185920);      // [4096][1024]
  u16* vb  = (u16*)(ws + 55574528);      // [4096][1024]
  float* biasg = (float*)(ws + 63963136); // [4][1024] f32
  u16* ab  = xb;                         // [8192][1024] aliases xb (dead after Q GEMM)

  build_bias<<<1, 256, 0, stream>>>(mask, biasg);
  cvt_bf16<<<8192, 256, 0, stream>>>(x, xb, 8388608);
  cvt_bf16<<<3072, 256, 0, stream>>>(ctx, cb, 3145728);
  transpose_cvt<<<dim3(32, 32), 256, 0, stream>>>(Wq, wqt, 1024, 1024);
  transpose_cvt<<<dim3(32, 24), 256, 0, stream>>>(Wk, wkt, 768, 1024);
  transpose_cvt<<<dim3(32, 24), 256, 0, stream>>>(Wv, wvt, 768, 1024);
  transpose_cvt<<<dim3(32, 32), 256, 0, stream>>>(Wo, wot, 1024, 1024);

  gemm_bt<1><<<dim3(8, 64), 256, 0, stream>>>(xb, wqt, qb, nullptr, 8192, 1024, 1024);
  gemm_bt<1><<<dim3(8, 32), 256, 0, stream>>>(cb, wkt, kb, nullptr, 4096, 1024, 768);
  gemm_bt<1><<<dim3(8, 32), 256, 0, stream>>>(cb, wvt, vb, nullptr, 4096, 1024, 768);

  attn<<<dim3(32, 16, 4), 256, 0, stream>>>(qb, kb, vb, biasg, ab);

  gemm_bt<0><<<dim3(8, 64), 256, 0, stream>>>(ab, wot, out, bo, 8192, 1024, 1024);
}

// Round 3
// 302.129 us; speedup vs baseline: 1.4268x; 1.4268x over previous
//
#include <hip/hip_runtime.h>

typedef unsigned short u16;
typedef __attribute__((ext_vector_type(8))) __bf16 bf16x8;
typedef __attribute__((ext_vector_type(4))) float f32x4;
typedef __attribute__((ext_vector_type(4))) u16 u16x4;

#define NB 4
#define NQ 2048
#define NKV 1024
#define NH 16
#define DH 64
#define DIN 1024   // INNER = h*d = query dim
#define DCTX 768
#define ATT_SCALE 0.125f
#define NEGBIG -1e30f

__device__ inline u16 f2bf(float f) {
  unsigned u = __builtin_bit_cast(unsigned, f);
  u += 0x7FFFu + ((u >> 16) & 1u);   // RNE (no NaN inputs here)
  return (u16)(u >> 16);
}

__device__ inline unsigned cvtpk(float lo, float hi) {
  unsigned r;
  asm("v_cvt_pk_bf16_f32 %0, %1, %2" : "=v"(r) : "v"(lo), "v"(hi));
  return r;
}

// ---------------- mask dtype detection + bias build ----------------
__global__ __launch_bounds__(256) void build_bias(const void* __restrict__ mask,
                                                  float* __restrict__ biasg) {
  __shared__ int notInt, notFloat;
  if (threadIdx.x == 0) { notInt = 0; notFloat = 0; }
  __syncthreads();
  const unsigned* mw = (const unsigned*)mask;
  int bad_i = 0, bad_f = 0;
#pragma unroll
  for (int e = 0; e < 4; e++) {
    unsigned v = mw[threadIdx.x * 4 + e];
    if (v > 1u) bad_i = 1;
    if (v != 0u && v != 0x3f800000u) bad_f = 1;
  }
  if (bad_i) atomicOr(&notInt, 1);
  if (bad_f) atomicOr(&notFloat, 1);
  __syncthreads();
  const int isInt = !notInt, isFloat = !notFloat;
  for (int i = threadIdx.x; i < NB * NKV; i += 256) {
    bool on;
    if (isInt)        on = ((const int*)mask)[i] != 0;
    else if (isFloat) on = ((const float*)mask)[i] != 0.f;
    else              on = ((const unsigned char*)mask)[i] != 0;
    biasg[i] = on ? 0.f : NEGBIG;
  }
}

// ---------------- fp32 -> bf16 elementwise ----------------
__global__ __launch_bounds__(256) void cvt_bf16(const float* __restrict__ in,
                                                u16* __restrict__ out, int n) {
  int i = (blockIdx.x * 256 + threadIdx.x) * 4;
  if (i >= n) return;
  float4 v = *(const float4*)(in + i);
  u16x4 o = { f2bf(v.x), f2bf(v.y), f2bf(v.z), f2bf(v.w) };
  *(u16x4*)(out + i) = o;
}

// ---------------- W[K][N] fp32 -> Wt[N][K] bf16 ----------------
__global__ __launch_bounds__(256) void transpose_cvt(const float* __restrict__ W,
                                                     u16* __restrict__ Wt, int K, int N) {
  __shared__ float tile[32][33];
  int n0 = blockIdx.x * 32, k0 = blockIdx.y * 32;
  int tx = threadIdx.x & 31, ty = threadIdx.x >> 5;  // 32 x 8
#pragma unroll
  for (int i = 0; i < 32; i += 8)
    tile[ty + i][tx] = W[(size_t)(k0 + ty + i) * N + n0 + tx];
  __syncthreads();
#pragma unroll
  for (int i = 0; i < 32; i += 8)
    Wt[(size_t)(n0 + ty + i) * K + k0 + tx] = f2bf(tile[tx][ty + i]);
}

// ---------------- bf16 GEMM: C[M][N] = A[M][K] * Bt[N][K]^T ----------------
template<int STORE_BF16>
__global__ __launch_bounds__(256) void gemm_bt(const u16* __restrict__ A,
                                               const u16* __restrict__ Bt,
                                               void* __restrict__ Cout,
                                               const float* __restrict__ bias,
                                               int M, int N, int K) {
  __shared__ __align__(16) u16 As[128 * 32];
  __shared__ __align__(16) u16 Bs[128 * 32];
  const int t = threadIdx.x, w = t >> 6, l = t & 63, g = l >> 4, m16 = l & 15;
  const int brow = blockIdx.y * 128, bcol = blockIdx.x * 128;
  const int wr = w >> 1, wc = w & 1;
  const int r_a = t >> 2;
  const int kb  = (t & 3) * 8;
  f32x4 acc[4][4] = {};

  for (int k0 = 0; k0 < K; k0 += 32) {
#pragma unroll
    for (int i = 0; i < 2; i++) {
      const u16* ga = A + (size_t)(brow + i * 64 + r_a) * K + k0 + kb;
      __builtin_amdgcn_global_load_lds((const __attribute__((address_space(1))) void*)ga,
          (__attribute__((address_space(3))) void*)((char*)As + i * 4096 + w * 1024), 16, 0, 0);
      const u16* gb = Bt + (size_t)(bcol + i * 64 + r_a) * K + k0 + kb;
      __builtin_amdgcn_global_load_lds((const __attribute__((address_space(1))) void*)gb,
          (__attribute__((address_space(3))) void*)((char*)Bs + i * 4096 + w * 1024), 16, 0, 0);
    }
    __syncthreads();
    bf16x8 af[4], bfr[4];
#pragma unroll
    for (int m = 0; m < 4; m++)
      af[m] = *(const bf16x8*)(As + (wr * 64 + m * 16 + m16) * 32 + g * 8);
#pragma unroll
    for (int n = 0; n < 4; n++)
      bfr[n] = *(const bf16x8*)(Bs + (wc * 64 + n * 16 + m16) * 32 + g * 8);
#pragma unroll
    for (int m = 0; m < 4; m++)
#pragma unroll
      for (int n = 0; n < 4; n++)
        acc[m][n] = __builtin_amdgcn_mfma_f32_16x16x32_bf16(af[m], bfr[n], acc[m][n], 0, 0, 0);
    __syncthreads();
  }
#pragma unroll
  for (int m = 0; m < 4; m++) {
    int grow = brow + wr * 64 + m * 16 + g * 4;
#pragma unroll
    for (int n = 0; n < 4; n++) {
      int gcol = bcol + wc * 64 + n * 16 + m16;
#pragma unroll
      for (int r = 0; r < 4; r++) {
        size_t off = (size_t)(grow + r) * N + gcol;
        if (STORE_BF16) ((u16*)Cout)[off] = f2bf(acc[m][n][r]);
        else            ((float*)Cout)[off] = acc[m][n][r] + bias[gcol];
      }
    }
  }
}

// ---------------- flash attention (swapped QK^T, fixed-max softmax) ----------------
// grid (16 qtiles, 16 heads, 4 batch), 256 thr = 4 waves
// QBLK=128 (wave w owns rows w*32..w*32+31 as two 16-row sets), KVBLK=64
__global__ __launch_bounds__(256) void attn(const u16* __restrict__ Q, const u16* __restrict__ Kb,
                                            const u16* __restrict__ Vb,
                                            const float* __restrict__ biasg,
                                            u16* __restrict__ O) {
  const int qt = blockIdx.x, h = blockIdx.y, b = blockIdx.z;
  const int t = threadIdx.x, w = t >> 6, l = t & 63, g = l >> 4, m16 = l & 15;

  __shared__ __align__(16) u16 Kl[64 * 64];        // [j][d], chunks XOR-swizzled by (j&7)
  __shared__ __align__(16) u16 Vt[64 * 64];        // [d][j], chunks XOR-swizzled by (d^(d>>3))&7
  __shared__ __align__(16) unsigned Pl[4][16 * 36]; // per-wave P (u32 pairs), row stride 36 words
  __shared__ float biasl[NKV];

  for (int i = t; i < NKV; i += 256) biasl[i] = biasg[(size_t)b * NKV + i];

  // Q fragments (B-operand): lane provides Q[i=m16][d = g*8+e (+32)]
  const int qrowA = qt * 128 + w * 32 + m16;
  const u16* qpA = Q + (size_t)(b * NQ + qrowA) * DIN + h * DH;
  bf16x8 qA0 = *(const bf16x8*)(qpA + g * 8);
  bf16x8 qA1 = *(const bf16x8*)(qpA + 32 + g * 8);
  const u16* qpB = qpA + 16 * DIN;
  bf16x8 qB0 = *(const bf16x8*)(qpB + g * 8);
  bf16x8 qB1 = *(const bf16x8*)(qpB + 32 + g * 8);

  f32x4 oA[4] = {}, oB[4] = {};
  float lA = 0.f, lB = 0.f;

  for (int j0 = 0; j0 < NKV; j0 += 64) {
    // ---- stage K: global_load_lds, LDS linear, source chunk pre-swizzled ----
#pragma unroll
    for (int n = 0; n < 2; n++) {
      int j = n * 32 + (t >> 3);
      int c = (t & 7) ^ (j & 7);
      const u16* gk = Kb + (size_t)(b * NKV + j0 + j) * DIN + h * DH + c * 8;
      __builtin_amdgcn_global_load_lds((const __attribute__((address_space(1))) void*)gk,
          (__attribute__((address_space(3))) void*)((char*)Kl + n * 4096 + t * 16), 16, 0, 0);
    }
    // ---- stage V: column-gather (coalesced per j-row), b128 row write ----
    {
      union { u16 e[16]; int4 q[2]; } vv;
      const u16* gv = Vb + (size_t)(b * NKV + j0 + w * 16) * DIN + h * DH + l;
#pragma unroll
      for (int e = 0; e < 16; e++) vv.e[e] = gv[(size_t)e * DIN];
      int swv = (l ^ (l >> 3)) & 7;
#pragma unroll
      for (int kk = 0; kk < 2; kk++) {
        int cp = (2 * w + kk) ^ swv;
        *(int4*)(Vt + l * 64 + cp * 8) = vv.q[kk];
      }
    }
    __syncthreads();

    // ---- QK^T (swapped): S^T[j][i], lane: i=m16, j = jt*16 + g*4 + r ----
    f32x4 sA[4], sB[4];
#pragma unroll
    for (int jt = 0; jt < 4; jt++) {
      int jr = jt * 16 + m16;
      const u16* krow = Kl + jr * 64;
      bf16x8 kf0 = *(const bf16x8*)(krow + ((g ^ (jr & 7)) * 8));
      bf16x8 kf1 = *(const bf16x8*)(krow + (((4 + g) ^ (jr & 7)) * 8));
      f32x4 z = {};
      f32x4 t0 = __builtin_amdgcn_mfma_f32_16x16x32_bf16(kf0, qA0, z, 0, 0, 0);
      sA[jt]   = __builtin_amdgcn_mfma_f32_16x16x32_bf16(kf1, qA1, t0, 0, 0, 0);
      f32x4 t1 = __builtin_amdgcn_mfma_f32_16x16x32_bf16(kf0, qB0, z, 0, 0, 0);
      sB[jt]   = __builtin_amdgcn_mfma_f32_16x16x32_bf16(kf1, qB1, t1, 0, 0, 0);
    }
    float4 b4[4];
#pragma unroll
    for (int jt = 0; jt < 4; jt++) b4[jt] = *(const float4*)&biasl[j0 + jt * 16 + g * 4];

    unsigned* plw = &Pl[w][0];
    // ---- set A: softmax (fixed max), pack, P round-trip, PV ----
    {
#pragma unroll
      for (int jt = 0; jt < 4; jt++) {
        float p0 = __expf(fmaf(sA[jt][0], ATT_SCALE, b4[jt].x));
        float p1 = __expf(fmaf(sA[jt][1], ATT_SCALE, b4[jt].y));
        float p2 = __expf(fmaf(sA[jt][2], ATT_SCALE, b4[jt].z));
        float p3 = __expf(fmaf(sA[jt][3], ATT_SCALE, b4[jt].w));
        lA += (p0 + p1) + (p2 + p3);
        uint2 u; u.x = cvtpk(p0, p1); u.y = cvtpk(p2, p3);
        *(uint2*)&plw[m16 * 36 + jt * 8 + 2 * g] = u;
      }
      asm volatile("" ::: "memory");
      bf16x8 pf0 = *(const bf16x8*)&plw[m16 * 36 + 4 * g];        // j = 8g..8g+7
      bf16x8 pf1 = *(const bf16x8*)&plw[m16 * 36 + 16 + 4 * g];   // j = 32+8g..+7
#pragma unroll
      for (int dt = 0; dt < 4; dt++) {
        int d = dt * 16 + m16;
        int swd = (d ^ (d >> 3)) & 7;
        const u16* vrow = Vt + d * 64;
        bf16x8 vf0 = *(const bf16x8*)(vrow + ((g ^ swd) * 8));
        bf16x8 vf1 = *(const bf16x8*)(vrow + (((4 + g) ^ swd) * 8));
        oA[dt] = __builtin_amdgcn_mfma_f32_16x16x32_bf16(pf0, vf0, oA[dt], 0, 0, 0);
        oA[dt] = __builtin_amdgcn_mfma_f32_16x16x32_bf16(pf1, vf1, oA[dt], 0, 0, 0);
      }
    }
    asm volatile("" ::: "memory");
    // ---- set B ----
    {
#pragma unroll
      for (int jt = 0; jt < 4; jt++) {
        float p0 = __expf(fmaf(sB[jt][0], ATT_SCALE, b4[jt].x));
        float p1 = __expf(fmaf(sB[jt][1], ATT_SCALE, b4[jt].y));
        float p2 = __expf(fmaf(sB[jt][2], ATT_SCALE, b4[jt].z));
        float p3 = __expf(fmaf(sB[jt][3], ATT_SCALE, b4[jt].w));
        lB += (p0 + p1) + (p2 + p3);
        uint2 u; u.x = cvtpk(p0, p1); u.y = cvtpk(p2, p3);
        *(uint2*)&plw[m16 * 36 + jt * 8 + 2 * g] = u;
      }
      asm volatile("" ::: "memory");
      bf16x8 pf0 = *(const bf16x8*)&plw[m16 * 36 + 4 * g];
      bf16x8 pf1 = *(const bf16x8*)&plw[m16 * 36 + 16 + 4 * g];
#pragma unroll
      for (int dt = 0; dt < 4; dt++) {
        int d = dt * 16 + m16;
        int swd = (d ^ (d >> 3)) & 7;
        const u16* vrow = Vt + d * 64;
        bf16x8 vf0 = *(const bf16x8*)(vrow + ((g ^ swd) * 8));
        bf16x8 vf1 = *(const bf16x8*)(vrow + (((4 + g) ^ swd) * 8));
        oB[dt] = __builtin_amdgcn_mfma_f32_16x16x32_bf16(pf0, vf0, oB[dt], 0, 0, 0);
        oB[dt] = __builtin_amdgcn_mfma_f32_16x16x32_bf16(pf1, vf1, oB[dt], 0, 0, 0);
      }
    }
    __syncthreads();
  }

  // ---- deferred l reduction: sum over g-groups; then fetch l for output rows ----
  lA += __shfl_xor(lA, 16); lA += __shfl_xor(lA, 32);
  lB += __shfl_xor(lB, 16); lB += __shfl_xor(lB, 32);
  float invA[4], invB[4];
#pragma unroll
  for (int r = 0; r < 4; r++) {
    invA[r] = 1.f / __shfl(lA, g * 4 + r);
    invB[r] = 1.f / __shfl(lB, g * 4 + r);
  }
  // output: O[row = g*4+r (+16 for B)][col = dt*16 + m16]
  u16* opA = O + (size_t)(b * NQ + qt * 128 + w * 32) * DIN + h * DH;
  u16* opB = opA + 16 * DIN;
#pragma unroll
  for (int dt = 0; dt < 4; dt++)
#pragma unroll
    for (int r = 0; r < 4; r++) {
      opA[(size_t)(g * 4 + r) * DIN + dt * 16 + m16] = f2bf(oA[dt][r] * invA[r]);
      opB[(size_t)(g * 4 + r) * DIN + dt * 16 + m16] = f2bf(oB[dt][r] * invB[r]);
    }
}

// ---------------- launcher ----------------
extern "C" void kernel_launch(void* const* d_in, const int* in_sizes, int n_in,
                              void* d_out, int out_size, void* d_ws, size_t ws_size,
                              hipStream_t stream) {
  const float* x   = (const float*)d_in[0];
  const float* ctx = (const float*)d_in[1];
  const void*  mask = (const void*)d_in[2];
  const float* Wq  = (const float*)d_in[3];
  const float* Wk  = (const float*)d_in[4];
  const float* Wv  = (const float*)d_in[5];
  const float* Wo  = (const float*)d_in[6];
  const float* bo  = (const float*)d_in[7];
  float* out = (float*)d_out;

  char* ws = (char*)d_ws;
  u16* xb  = (u16*)(ws);                 // [8192][1024] bf16 (reused as ab after Q GEMM)
  u16* cb  = (u16*)(ws + 16777216);      // [4096][768]
  u16* wqt = (u16*)(ws + 23068672);      // [1024][1024]
  u16* wkt = (u16*)(ws + 25165824);      // [1024][768]
  u16* wvt = (u16*)(ws + 26738688);      // [1024][768]
  u16* wot = (u16*)(ws + 28311552);      // [1024][1024]
  u16* qb  = (u16*)(ws + 30408704);      // [8192][1024]
  u16* kb  = (u16*)(ws + 47185920);      // [4096][1024]
  u16* vb  = (u16*)(ws + 55574528);      // [4096][1024]
  float* biasg = (float*)(ws + 63963136); // [4][1024] f32
  u16* ab  = xb;

  build_bias<<<1, 256, 0, stream>>>(mask, biasg);
  cvt_bf16<<<8192, 256, 0, stream>>>(x, xb, 8388608);
  cvt_bf16<<<3072, 256, 0, stream>>>(ctx, cb, 3145728);
  transpose_cvt<<<dim3(32, 32), 256, 0, stream>>>(Wq, wqt, 1024, 1024);
  transpose_cvt<<<dim3(32, 24), 256, 0, stream>>>(Wk, wkt, 768, 1024);
  transpose_cvt<<<dim3(32, 24), 256, 0, stream>>>(Wv, wvt, 768, 1024);
  transpose_cvt<<<dim3(32, 32), 256, 0, stream>>>(Wo, wot, 1024, 1024);

  gemm_bt<1><<<dim3(8, 64), 256, 0, stream>>>(xb, wqt, qb, nullptr, 8192, 1024, 1024);
  gemm_bt<1><<<dim3(8, 32), 256, 0, stream>>>(cb, wkt, kb, nullptr, 4096, 1024, 768);
  gemm_bt<1><<<dim3(8, 32), 256, 0, stream>>>(cb, wvt, vb, nullptr, 4096, 1024, 768);

  attn<<<dim3(16, 16, 4), 256, 0, stream>>>(qb, kb, vb, biasg, ab);

  gemm_bt<0><<<dim3(8, 64), 256, 0, stream>>>(ab, wot, out, bo, 8192, 1024, 1024);
}

// Round 4
// 275.021 us; speedup vs baseline: 1.5675x; 1.0986x over previous
//
#include <hip/hip_runtime.h>

typedef unsigned short u16;
typedef __attribute__((ext_vector_type(8))) __bf16 bf16x8;
typedef __attribute__((ext_vector_type(4))) float f32x4;
typedef __attribute__((ext_vector_type(4))) u16 u16x4;

#define NB 4
#define NQ 2048
#define NKV 1024
#define NH 16
#define DH 64
#define DIN 1024
#define DCTX 768
#define NEGBIG -1e30f
#define QSC 0.180336881f   // 0.125 * log2(e): softmax scale folded into Q, exp -> exp2

__device__ inline u16 f2bf(float f) {
  unsigned u = __builtin_bit_cast(unsigned, f);
  u += 0x7FFFu + ((u >> 16) & 1u);
  return (u16)(u >> 16);
}

__device__ inline unsigned cvtpk(float lo, float hi) {
  unsigned r;
  asm("v_cvt_pk_bf16_f32 %0, %1, %2" : "=v"(r) : "v"(lo), "v"(hi));
  return r;
}

__device__ inline float exp2a(float x) {  // v_exp_f32 computes 2^x natively
  float r;
  asm("v_exp_f32 %0, %1" : "=v"(r) : "v"(x));
  return r;
}

// ---------------- mask dtype detection + bias build ----------------
__global__ __launch_bounds__(256) void build_bias(const void* __restrict__ mask,
                                                  float* __restrict__ biasg) {
  __shared__ int notInt, notFloat;
  if (threadIdx.x == 0) { notInt = 0; notFloat = 0; }
  __syncthreads();
  const unsigned* mw = (const unsigned*)mask;
  int bad_i = 0, bad_f = 0;
#pragma unroll
  for (int e = 0; e < 4; e++) {
    unsigned v = mw[threadIdx.x * 4 + e];
    if (v > 1u) bad_i = 1;
    if (v != 0u && v != 0x3f800000u) bad_f = 1;
  }
  if (bad_i) atomicOr(&notInt, 1);
  if (bad_f) atomicOr(&notFloat, 1);
  __syncthreads();
  const int isInt = !notInt, isFloat = !notFloat;
  for (int i = threadIdx.x; i < NB * NKV; i += 256) {
    bool on;
    if (isInt)        on = ((const int*)mask)[i] != 0;
    else if (isFloat) on = ((const float*)mask)[i] != 0.f;
    else              on = ((const unsigned char*)mask)[i] != 0;
    biasg[i] = on ? 0.f : NEGBIG;
  }
}

// ---------------- fp32 -> bf16 elementwise ----------------
__global__ __launch_bounds__(256) void cvt_bf16(const float* __restrict__ in,
                                                u16* __restrict__ out, int n) {
  int i = (blockIdx.x * 256 + threadIdx.x) * 4;
  if (i >= n) return;
  float4 v = *(const float4*)(in + i);
  u16x4 o = { f2bf(v.x), f2bf(v.y), f2bf(v.z), f2bf(v.w) };
  *(u16x4*)(out + i) = o;
}

// ---------------- W[K][N] fp32 -> Wt[N][K] bf16 ----------------
__global__ __launch_bounds__(256) void transpose_cvt(const float* __restrict__ W,
                                                     u16* __restrict__ Wt, int K, int N) {
  __shared__ float tile[32][33];
  int n0 = blockIdx.x * 32, k0 = blockIdx.y * 32;
  int tx = threadIdx.x & 31, ty = threadIdx.x >> 5;
#pragma unroll
  for (int i = 0; i < 32; i += 8)
    tile[ty + i][tx] = W[(size_t)(k0 + ty + i) * N + n0 + tx];
  __syncthreads();
#pragma unroll
  for (int i = 0; i < 32; i += 8)
    Wt[(size_t)(n0 + ty + i) * K + k0 + tx] = f2bf(tile[tx][ty + i]);
}

// ---------------- bf16 GEMM: C = A * Bt^T, 2-phase prefetch, dbuf LDS ----------------
// STORE_MODE: 0 = f32 + bias, 1 = bf16, 2 = bf16 * QSC (Q pre-scale)
template<int STORE_MODE>
__global__ __launch_bounds__(256) void gemm_bt(const u16* __restrict__ A,
                                               const u16* __restrict__ Bt,
                                               void* __restrict__ Cout,
                                               const float* __restrict__ bias,
                                               int M, int N, int K) {
  __shared__ __align__(16) u16 As[2][128 * 32];
  __shared__ __align__(16) u16 Bs[2][128 * 32];
  const int t = threadIdx.x, w = t >> 6, l = t & 63, g = l >> 4, m16 = l & 15;
  const int brow = blockIdx.y * 128, bcol = blockIdx.x * 128;
  const int wr = w >> 1, wc = w & 1;
  const int r_a = t >> 2;
  const int kb  = (t & 3) * 8;
  const int nk = K >> 5;
  f32x4 acc[4][4] = {};

#define G_STAGE(ks, bsel)                                                              \
  {                                                                                    \
    int k0_ = (ks) << 5;                                                               \
    _Pragma("unroll")                                                                  \
    for (int i = 0; i < 2; i++) {                                                      \
      const u16* ga = A + (size_t)(brow + i * 64 + r_a) * K + k0_ + kb;                \
      __builtin_amdgcn_global_load_lds(                                                \
          (const __attribute__((address_space(1))) void*)ga,                           \
          (__attribute__((address_space(3))) void*)((char*)As + (bsel) * 8192 + i * 4096 + w * 1024), \
          16, 0, 0);                                                                   \
      const u16* gb = Bt + (size_t)(bcol + i * 64 + r_a) * K + k0_ + kb;               \
      __builtin_amdgcn_global_load_lds(                                                \
          (const __attribute__((address_space(1))) void*)gb,                           \
          (__attribute__((address_space(3))) void*)((char*)Bs + (bsel) * 8192 + i * 4096 + w * 1024), \
          16, 0, 0);                                                                   \
    }                                                                                  \
  }

  G_STAGE(0, 0);
  asm volatile("s_waitcnt vmcnt(0)" ::: "memory");
  __builtin_amdgcn_s_barrier();

  for (int ks = 0; ks < nk; ++ks) {
    const int cur = ks & 1;
    bf16x8 af[4], bfr[4];
#pragma unroll
    for (int m = 0; m < 4; m++)
      af[m] = *(const bf16x8*)(&As[cur][(wr * 64 + m * 16 + m16) * 32 + g * 8]);
#pragma unroll
    for (int n = 0; n < 4; n++)
      bfr[n] = *(const bf16x8*)(&Bs[cur][(wc * 64 + n * 16 + m16) * 32 + g * 8]);
    if (ks + 1 < nk) G_STAGE(ks + 1, cur ^ 1);
#pragma unroll
    for (int m = 0; m < 4; m++)
#pragma unroll
      for (int n = 0; n < 4; n++)
        acc[m][n] = __builtin_amdgcn_mfma_f32_16x16x32_bf16(af[m], bfr[n], acc[m][n], 0, 0, 0);
    asm volatile("s_waitcnt vmcnt(0)" ::: "memory");
    __builtin_amdgcn_s_barrier();
  }
#undef G_STAGE

#pragma unroll
  for (int m = 0; m < 4; m++) {
    int grow = brow + wr * 64 + m * 16 + g * 4;
#pragma unroll
    for (int n = 0; n < 4; n++) {
      int gcol = bcol + wc * 64 + n * 16 + m16;
#pragma unroll
      for (int r = 0; r < 4; r++) {
        size_t off = (size_t)(grow + r) * N + gcol;
        if (STORE_MODE == 0)      ((float*)Cout)[off] = acc[m][n][r] + bias[gcol];
        else if (STORE_MODE == 1) ((u16*)Cout)[off] = f2bf(acc[m][n][r]);
        else                      ((u16*)Cout)[off] = f2bf(acc[m][n][r] * QSC);
      }
    }
  }
}

// ---------------- flash attention ----------------
// swapped QK^T, fixed-max softmax (Q pre-scaled by 0.125*log2e, p = 2^(s+bias)),
// dbuf K (global_load_lds) + V (reg-gather, async-STAGE split), ONE barrier/tile.
// grid (16 qtiles, 16 heads, 4 batch), 256 thr = 4 waves, QBLK=128, KVBLK=64
__global__ __launch_bounds__(256) void attn(const u16* __restrict__ Q, const u16* __restrict__ Kb,
                                            const u16* __restrict__ Vb,
                                            const float* __restrict__ biasg,
                                            u16* __restrict__ O, int kvs) {
  const int qt = blockIdx.x, h = blockIdx.y, b = blockIdx.z;
  const int t = threadIdx.x, w = t >> 6, l = t & 63, g = l >> 4, m16 = l & 15;

  __shared__ __align__(16) u16 Kl[2][64 * 64];
  __shared__ __align__(16) u16 Vt[2][64 * 64];
  __shared__ __align__(16) unsigned Pl[4][16 * 36];
  __shared__ float biasl[NKV];

  for (int i = t; i < NKV; i += 256) biasl[i] = biasg[(size_t)b * NKV + i];

  const int qrowA = qt * 128 + w * 32 + m16;
  const u16* qpA = Q + (size_t)(b * NQ + qrowA) * DIN + h * DH;
  bf16x8 qA0 = *(const bf16x8*)(qpA + g * 8);
  bf16x8 qA1 = *(const bf16x8*)(qpA + 32 + g * 8);
  const u16* qpB = qpA + 16 * DIN;
  bf16x8 qB0 = *(const bf16x8*)(qpB + g * 8);
  bf16x8 qB1 = *(const bf16x8*)(qpB + 32 + g * 8);

  f32x4 oA[4] = {}, oB[4] = {};
  float lA = 0.f, lB = 0.f;

  union VV { u16 e[16]; int4 q[2]; };
  VV vv;
  const int swv = (l ^ (l >> 3)) & 7;

#define GATHER_V(j0)                                                          \
  {                                                                           \
    const u16* gv = Vb + (size_t)(b * NKV + (j0) + w * 16) * kvs + h * DH + l; \
    _Pragma("unroll")                                                         \
    for (int e = 0; e < 16; e++) vv.e[e] = gv[(size_t)e * kvs];               \
  }
#define STAGE_K(j0, bsel)                                                     \
  {                                                                           \
    _Pragma("unroll")                                                         \
    for (int n = 0; n < 2; n++) {                                             \
      int j_ = n * 32 + (t >> 3);                                             \
      int c_ = (t & 7) ^ (j_ & 7);                                            \
      const u16* gk = Kb + (size_t)(b * NKV + (j0) + j_) * kvs + h * DH + c_ * 8; \
      __builtin_amdgcn_global_load_lds(                                       \
          (const __attribute__((address_space(1))) void*)gk,                  \
          (__attribute__((address_space(3))) void*)((char*)Kl + (bsel) * 8192 + n * 4096 + t * 16), \
          16, 0, 0);                                                          \
    }                                                                         \
  }
#define WRITE_V(bsel)                                                         \
  {                                                                           \
    _Pragma("unroll")                                                         \
    for (int kk = 0; kk < 2; kk++) {                                          \
      int cp = (2 * w + kk) ^ swv;                                            \
      *(int4*)(&Vt[bsel][l * 64 + cp * 8]) = vv.q[kk];                        \
    }                                                                         \
  }

  GATHER_V(0);
  STAGE_K(0, 0);
  asm volatile("s_waitcnt vmcnt(0)" ::: "memory");
  WRITE_V(0);
  asm volatile("s_waitcnt lgkmcnt(0)" ::: "memory");
  __builtin_amdgcn_s_barrier();

  for (int it = 0; it < 16; ++it) {
    const int cur = it & 1, nxt = cur ^ 1;
    const int j0 = it * 64;
    if (it + 1 < 16) {
      GATHER_V(j0 + 64);
      STAGE_K(j0 + 64, nxt);
    }

    // ---- QK^T (swapped): lane holds S^T[j][i], i=m16 ----
    f32x4 sA[4], sB[4];
#pragma unroll
    for (int jt = 0; jt < 4; jt++) {
      int jr = jt * 16 + m16;
      const u16* krow = &Kl[cur][jr * 64];
      bf16x8 kf0 = *(const bf16x8*)(krow + ((g ^ (jr & 7)) * 8));
      bf16x8 kf1 = *(const bf16x8*)(krow + (((4 + g) ^ (jr & 7)) * 8));
      f32x4 z = {};
      f32x4 t0 = __builtin_amdgcn_mfma_f32_16x16x32_bf16(kf0, qA0, z, 0, 0, 0);
      sA[jt]   = __builtin_amdgcn_mfma_f32_16x16x32_bf16(kf1, qA1, t0, 0, 0, 0);
      f32x4 t1 = __builtin_amdgcn_mfma_f32_16x16x32_bf16(kf0, qB0, z, 0, 0, 0);
      sB[jt]   = __builtin_amdgcn_mfma_f32_16x16x32_bf16(kf1, qB1, t1, 0, 0, 0);
    }
    float4 b4[4];
#pragma unroll
    for (int jt = 0; jt < 4; jt++) b4[jt] = *(const float4*)&biasl[j0 + jt * 16 + g * 4];

    unsigned* plw = &Pl[w][0];
    // ---- set A ----
    {
#pragma unroll
      for (int jt = 0; jt < 4; jt++) {
        float p0 = exp2a(sA[jt][0] + b4[jt].x);
        float p1 = exp2a(sA[jt][1] + b4[jt].y);
        float p2 = exp2a(sA[jt][2] + b4[jt].z);
        float p3 = exp2a(sA[jt][3] + b4[jt].w);
        lA += (p0 + p1) + (p2 + p3);
        uint2 u; u.x = cvtpk(p0, p1); u.y = cvtpk(p2, p3);
        *(uint2*)&plw[m16 * 36 + jt * 8 + 2 * g] = u;
      }
      asm volatile("" ::: "memory");
      bf16x8 pf0 = *(const bf16x8*)&plw[m16 * 36 + 4 * g];
      bf16x8 pf1 = *(const bf16x8*)&plw[m16 * 36 + 16 + 4 * g];
#pragma unroll
      for (int dt = 0; dt < 4; dt++) {
        int d = dt * 16 + m16;
        int swd = (d ^ (d >> 3)) & 7;
        const u16* vrow = &Vt[cur][d * 64];
        bf16x8 vf0 = *(const bf16x8*)(vrow + ((g ^ swd) * 8));
        bf16x8 vf1 = *(const bf16x8*)(vrow + (((4 + g) ^ swd) * 8));
        oA[dt] = __builtin_amdgcn_mfma_f32_16x16x32_bf16(pf0, vf0, oA[dt], 0, 0, 0);
        oA[dt] = __builtin_amdgcn_mfma_f32_16x16x32_bf16(pf1, vf1, oA[dt], 0, 0, 0);
      }
    }
    asm volatile("" ::: "memory");
    // ---- set B ----
    {
#pragma unroll
      for (int jt = 0; jt < 4; jt++) {
        float p0 = exp2a(sB[jt][0] + b4[jt].x);
        float p1 = exp2a(sB[jt][1] + b4[jt].y);
        float p2 = exp2a(sB[jt][2] + b4[jt].z);
        float p3 = exp2a(sB[jt][3] + b4[jt].w);
        lB += (p0 + p1) + (p2 + p3);
        uint2 u; u.x = cvtpk(p0, p1); u.y = cvtpk(p2, p3);
        *(uint2*)&plw[m16 * 36 + jt * 8 + 2 * g] = u;
      }
      asm volatile("" ::: "memory");
      bf16x8 pf0 = *(const bf16x8*)&plw[m16 * 36 + 4 * g];
      bf16x8 pf1 = *(const bf16x8*)&plw[m16 * 36 + 16 + 4 * g];
#pragma unroll
      for (int dt = 0; dt < 4; dt++) {
        int d = dt * 16 + m16;
        int swd = (d ^ (d >> 3)) & 7;
        const u16* vrow = &Vt[cur][d * 64];
        bf16x8 vf0 = *(const bf16x8*)(vrow + ((g ^ swd) * 8));
        bf16x8 vf1 = *(const bf16x8*)(vrow + (((4 + g) ^ swd) * 8));
        oB[dt] = __builtin_amdgcn_mfma_f32_16x16x32_bf16(pf0, vf0, oB[dt], 0, 0, 0);
        oB[dt] = __builtin_amdgcn_mfma_f32_16x16x32_bf16(pf1, vf1, oB[dt], 0, 0, 0);
      }
    }
    asm volatile("s_waitcnt vmcnt(0)" ::: "memory");
    if (it + 1 < 16) WRITE_V(nxt);
    asm volatile("s_waitcnt lgkmcnt(0)" ::: "memory");
    __builtin_amdgcn_s_barrier();
  }
#undef GATHER_V
#undef STAGE_K
#undef WRITE_V

  lA += __shfl_xor(lA, 16); lA += __shfl_xor(lA, 32);
  lB += __shfl_xor(lB, 16); lB += __shfl_xor(lB, 32);
  float invA[4], invB[4];
#pragma unroll
  for (int r = 0; r < 4; r++) {
    invA[r] = 1.f / __shfl(lA, g * 4 + r);
    invB[r] = 1.f / __shfl(lB, g * 4 + r);
  }
  u16* opA = O + (size_t)(b * NQ + qt * 128 + w * 32) * DIN + h * DH;
  u16* opB = opA + 16 * DIN;
#pragma unroll
  for (int dt = 0; dt < 4; dt++)
#pragma unroll
    for (int r = 0; r < 4; r++) {
      opA[(size_t)(g * 4 + r) * DIN + dt * 16 + m16] = f2bf(oA[dt][r] * invA[r]);
      opB[(size_t)(g * 4 + r) * DIN + dt * 16 + m16] = f2bf(oB[dt][r] * invB[r]);
    }
}

// ---------------- launcher ----------------
extern "C" void kernel_launch(void* const* d_in, const int* in_sizes, int n_in,
                              void* d_out, int out_size, void* d_ws, size_t ws_size,
                              hipStream_t stream) {
  const float* x   = (const float*)d_in[0];
  const float* ctx = (const float*)d_in[1];
  const void*  mask = (const void*)d_in[2];
  const float* Wq  = (const float*)d_in[3];
  const float* Wk  = (const float*)d_in[4];
  const float* Wv  = (const float*)d_in[5];
  const float* Wo  = (const float*)d_in[6];
  const float* bo  = (const float*)d_in[7];
  float* out = (float*)d_out;

  char* ws = (char*)d_ws;
  u16* xb   = (u16*)(ws);                  // [8192][1024] bf16 (reused as ab)
  u16* cb   = (u16*)(ws + 16777216);       // [4096][768]
  u16* wqt  = (u16*)(ws + 23068672);       // [1024][1024]
  u16* wkv  = (u16*)(ws + 25165824);       // [2048][768]  (Wk^T rows 0-1023, Wv^T rows 1024-2047)
  u16* wot  = (u16*)(ws + 28311552);       // [1024][1024]
  u16* qb   = (u16*)(ws + 30408704);       // [8192][1024]
  u16* kvb  = (u16*)(ws + 47185920);       // [4096][2048] (cols 0-1023 = K, 1024-2047 = V)
  float* biasg = (float*)(ws + 63963136);  // [4][1024]
  u16* ab   = xb;

  build_bias<<<1, 256, 0, stream>>>(mask, biasg);
  cvt_bf16<<<8192, 256, 0, stream>>>(x, xb, 8388608);
  cvt_bf16<<<3072, 256, 0, stream>>>(ctx, cb, 3145728);
  transpose_cvt<<<dim3(32, 32), 256, 0, stream>>>(Wq, wqt, 1024, 1024);
  transpose_cvt<<<dim3(32, 24), 256, 0, stream>>>(Wk, wkv, 768, 1024);
  transpose_cvt<<<dim3(32, 24), 256, 0, stream>>>(Wv, wkv + 1024 * 768, 768, 1024);
  transpose_cvt<<<dim3(32, 32), 256, 0, stream>>>(Wo, wot, 1024, 1024);

  gemm_bt<2><<<dim3(8, 64), 256, 0, stream>>>(xb, wqt, qb, nullptr, 8192, 1024, 1024);   // Q (pre-scaled)
  gemm_bt<1><<<dim3(16, 32), 256, 0, stream>>>(cb, wkv, kvb, nullptr, 4096, 2048, 768);  // K|V fused

  attn<<<dim3(16, 16, 4), 256, 0, stream>>>(qb, kvb, kvb + 1024, biasg, ab, 2048);

  gemm_bt<0><<<dim3(8, 64), 256, 0, stream>>>(ab, wot, out, bo, 8192, 1024, 1024);       // O + bias
}